// Round 2
// baseline (2459.518 us; speedup 1.0000x reference)
//
#include <hip/hip_runtime.h>
#include <math.h>

#define IN    64
#define UNITS 50
#define BBU   128
#define BATCH 256
#define TT    2048
#define NOUT  150   // 50 ff1 + 50 ff2 + 50 t-combined

// ---------------------------------------------------------------------------
// Kernel A (parallel): xproj[t][j] = b_bb[j] + sum_k x[255,t,k] * W_bb[k,j]
// ---------------------------------------------------------------------------
__global__ void xproj_kernel(const float* __restrict__ x,
                             const float* __restrict__ W_bb,
                             const float* __restrict__ b_bb,
                             float* __restrict__ xproj) {
    __shared__ float xr[IN];
    const int t = blockIdx.x;
    const int j = threadIdx.x;  // 0..127
    const float* xrow = x + ((size_t)(BATCH - 1) * TT + t) * IN;
    if (j < IN) xr[j] = xrow[j];
    __syncthreads();
    float acc = b_bb[j];
    #pragma unroll
    for (int k = 0; k < IN; ++k) acc = fmaf(xr[k], W_bb[k * BBU + j], acc);
    xproj[t * BBU + j] = acc;
}

// ---------------------------------------------------------------------------
// Kernel B (sequential): persistent single block, 512 threads (8 waves).
// Per step:
//   phase1: bb[j]  = 1.7159*tanh(0.666*(xproj[t][j] + sum_u h[u]*Wh[u][j]))
//           (4 lanes per j, 13/13/13/11 MAC split, shfl-reduce)
//   phase2: p[o]   = bias[o] + sum_i bb[i]*W2[i][o], o<150
//           (2 lanes per o, 64 MACs each, shfl-reduce; reducer applies
//            tanh (o<100) or sigmoid (o>=100))
//   phase3: h[u]   = ff1 + t*(ff2-ff1)   (50 lanes)
// ---------------------------------------------------------------------------
__launch_bounds__(512, 1)
__global__ void cfc_seq_kernel(const float* __restrict__ W_bb,
                               const float* __restrict__ W_ff1, const float* __restrict__ b_ff1,
                               const float* __restrict__ W_ff2, const float* __restrict__ b_ff2,
                               const float* __restrict__ W_ta,  const float* __restrict__ b_ta,
                               const float* __restrict__ W_tb,  const float* __restrict__ b_tb,
                               const float* __restrict__ W_out, const float* __restrict__ b_out,
                               const float* __restrict__ xproj,
                               float* __restrict__ out) {
    __shared__ float h_lds[56];                      // h padded, [50..55] = 0
    __shared__ __align__(16) float bb_lds[BBU];
    __shared__ float n_lds[152];                     // nonlinearity outputs

    const int tid = threadIdx.x;

    // ---- phase-1 mapping: j1 = tid>>2 (0..127), s1 = tid&3, u in [u0,u0+13)
    const int j1 = tid >> 2;
    const int s1 = tid & 3;
    const int u0 = s1 * 13;
    float wh[13];
    #pragma unroll
    for (int q = 0; q < 13; ++q) {
        const int u = u0 + q;
        wh[q] = (u < UNITS) ? W_bb[(IN + u) * BBU + j1] : 0.f;
    }

    // ---- phase-2 mapping: o2 = tid>>1 (0..149), s2 = tid&1, i in [64*s2, 64*s2+64)
    const int o2 = tid >> 1;
    const int s2 = tid & 1;
    const bool p2act = (tid < 2 * NOUT);
    float w2[64];
    float bias2 = 0.f;
    if (p2act) {
        const float* Wsrc;
        const float* Wsrc2 = nullptr;
        int col;
        if (o2 < 50)       { Wsrc = W_ff1; col = o2;       bias2 = b_ff1[col]; }
        else if (o2 < 100) { Wsrc = W_ff2; col = o2 - 50;  bias2 = b_ff2[col]; }
        else               { Wsrc = W_ta;  Wsrc2 = W_tb; col = o2 - 100;
                             bias2 = b_ta[col] + b_tb[col]; }
        #pragma unroll
        for (int r = 0; r < 64; ++r) {
            const int i = s2 * 64 + r;
            float w = Wsrc[i * UNITS + col];
            if (Wsrc2) w += Wsrc2[i * UNITS + col];
            w2[r] = w;
        }
    } else {
        #pragma unroll
        for (int r = 0; r < 64; ++r) w2[r] = 0.f;
    }

    if (tid < 56) h_lds[tid] = 0.f;

    float xp_cur = 0.f, xp_next = 0.f;
    if (s1 == 0) xp_cur = xproj[j1];   // t = 0
    __syncthreads();

    for (int t = 0; t < TT; ++t) {
        // prefetch next step's xproj (used next iteration -> latency hidden)
        if (s1 == 0) {
            const int tn = (t + 1 < TT) ? (t + 1) : t;
            xp_next = xproj[tn * BBU + j1];
        }

        // ---- phase 1: recurrent part of backbone
        float acc = (s1 == 0) ? xp_cur : 0.f;
        #pragma unroll
        for (int q = 0; q < 13; ++q)
            acc = fmaf(h_lds[u0 + q], wh[q], acc);
        acc += __shfl_xor(acc, 1);
        acc += __shfl_xor(acc, 2);
        if (s1 == 0)
            bb_lds[j1] = 1.7159f * tanhf(0.666f * acc);
        __syncthreads();

        // ---- phase 2: three head projections + nonlinearity
        if (p2act) {
            float a2 = (s2 == 0) ? bias2 : 0.f;
            const float4* bb4 = (const float4*)bb_lds;
            #pragma unroll
            for (int r = 0; r < 16; ++r) {
                const float4 v = bb4[s2 * 16 + r];
                a2 = fmaf(v.x, w2[4 * r + 0], a2);
                a2 = fmaf(v.y, w2[4 * r + 1], a2);
                a2 = fmaf(v.z, w2[4 * r + 2], a2);
                a2 = fmaf(v.w, w2[4 * r + 3], a2);
            }
            a2 += __shfl_xor(a2, 1);
            if (s2 == 0) {
                float nv;
                if (o2 < 100) nv = tanhf(a2);
                else          nv = 1.f / (1.f + expf(-a2));
                n_lds[o2] = nv;
            }
        }
        __syncthreads();

        // ---- phase 3: hidden-state update
        if (tid < UNITS) {
            const float f1 = n_lds[tid];
            const float f2 = n_lds[50 + tid];
            const float ti = n_lds[100 + tid];
            h_lds[tid] = f1 + ti * (f2 - f1);
        }
        xp_cur = xp_next;
        __syncthreads();
    }

    // ---- readout: out = h @ W_out + b_out  (single wave)
    if (tid < 64) {
        float v = (tid < UNITS) ? h_lds[tid] * W_out[tid] : 0.f;
        #pragma unroll
        for (int off = 1; off < 64; off <<= 1)
            v += __shfl_xor(v, off);
        if (tid == 0) out[0] = v + b_out[0];
    }
}

// ---------------------------------------------------------------------------
extern "C" void kernel_launch(void* const* d_in, const int* in_sizes, int n_in,
                              void* d_out, int out_size, void* d_ws, size_t ws_size,
                              hipStream_t stream) {
    const float* x     = (const float*)d_in[0];
    const float* W_bb  = (const float*)d_in[1];
    const float* b_bb  = (const float*)d_in[2];
    const float* W_ff1 = (const float*)d_in[3];
    const float* b_ff1 = (const float*)d_in[4];
    const float* W_ff2 = (const float*)d_in[5];
    const float* b_ff2 = (const float*)d_in[6];
    const float* W_ta  = (const float*)d_in[7];
    const float* b_ta  = (const float*)d_in[8];
    const float* W_tb  = (const float*)d_in[9];
    const float* b_tb  = (const float*)d_in[10];
    const float* W_out = (const float*)d_in[11];
    const float* b_out = (const float*)d_in[12];
    float* out = (float*)d_out;

    float* xproj = (float*)d_ws;   // TT * BBU floats = 1 MiB

    xproj_kernel<<<TT, BBU, 0, stream>>>(x, W_bb, b_bb, xproj);
    cfc_seq_kernel<<<1, 512, 0, stream>>>(W_bb,
                                          W_ff1, b_ff1, W_ff2, b_ff2,
                                          W_ta, b_ta, W_tb, b_tb,
                                          W_out, b_out, xproj, out);
}

// Round 4
// 1961.960 us; speedup vs baseline: 1.2536x; 1.2536x over previous
//
#include <hip/hip_runtime.h>
#include <math.h>

#define IN    64
#define UNITS 50
#define BBU   128
#define BATCH 256
#define TT    2048

// ---------------------------------------------------------------------------
// DPP cross-lane helpers (VALU pipe, ~4 cyc — NOT the LDS pipe like __shfl)
// quad_perm xor1 = [1,0,3,2] = 0xB1 ; xor2 = [2,3,0,1] = 0x4E
// ---------------------------------------------------------------------------
__device__ __forceinline__ float dpp_xor1(float v) {
    int r = __builtin_amdgcn_update_dpp(0, __builtin_bit_cast(int, v),
                                        0xB1, 0xF, 0xF, true);
    return __builtin_bit_cast(float, r);
}
__device__ __forceinline__ float dpp_xor2(float v) {
    int r = __builtin_amdgcn_update_dpp(0, __builtin_bit_cast(int, v),
                                        0x4E, 0xF, 0xF, true);
    return __builtin_bit_cast(float, r);
}

// ---------------------------------------------------------------------------
// Kernel A (parallel): xproj[t][j] = b_bb[j] + sum_k x[255,t,k] * W_bb[k,j]
// ---------------------------------------------------------------------------
__global__ void xproj_kernel(const float* __restrict__ x,
                             const float* __restrict__ W_bb,
                             const float* __restrict__ b_bb,
                             float* __restrict__ xproj) {
    __shared__ float xr[IN];
    const int t = blockIdx.x;
    const int j = threadIdx.x;  // 0..127
    const float* xrow = x + ((size_t)(BATCH - 1) * TT + t) * IN;
    if (j < IN) xr[j] = xrow[j];
    __syncthreads();
    float acc = b_bb[j];
    #pragma unroll
    for (int k = 0; k < IN; ++k) acc = fmaf(xr[k], W_bb[k * BBU + j], acc);
    xproj[t * BBU + j] = acc;
}

// ---------------------------------------------------------------------------
// Kernel B (sequential): 1 block, 256 threads (4 waves), 2 barriers/step.
//
// Phase 1 (all 256 lanes): j = tid>>1 (0..127), s = tid&1.
//   Each lane: 25 recurrent MACs (units s*25..s*25+24), pair-reduce via
//   DPP xor1, lecun_tanh, s==0 lane writes bb_lds[j].
// Phase 2 (lanes tid<200 carry real weights; all lanes execute uniformly):
//   quad q = tid>>2 (unit, q<50), r = tid&3.
//   r=0: ff1 dot (128 MACs, 4 accumulators), r=1: ff2, r=2: ta+tb, r=3 dead.
//   Unified activation: val = 1 - c*rcp(exp2(k*a)+1)  (tanh or sigmoid).
//   DPP xor1/xor2 gather f2,ti onto r=0 which computes h and writes h_lds.
// h layout: unit u at slot u + 7*(u>=25)  (each 25-run 128B-aligned at s*32)
// ---------------------------------------------------------------------------
__launch_bounds__(256, 1)
__global__ void cfc_seq_kernel(const float* __restrict__ W_bb,
                               const float* __restrict__ W_ff1, const float* __restrict__ b_ff1,
                               const float* __restrict__ W_ff2, const float* __restrict__ b_ff2,
                               const float* __restrict__ W_ta,  const float* __restrict__ b_ta,
                               const float* __restrict__ W_tb,  const float* __restrict__ b_tb,
                               const float* __restrict__ W_out, const float* __restrict__ b_out,
                               const float* __restrict__ xproj,
                               float* __restrict__ out) {
    __shared__ float h_lds[64];                       // padded 2x32 layout
    __shared__ __align__(16) float bb_lds[BBU];

    const int tid = threadIdx.x;

    // ---- phase-1 weights: 25 recurrent weights per lane
    const int j1 = tid >> 1;
    const int s1 = tid & 1;
    float wh[25];
    #pragma unroll
    for (int q = 0; q < 25; ++q)
        wh[q] = W_bb[(IN + s1 * 25 + q) * BBU + j1];
    const int hbase = s1 * 32;

    // ---- phase-2 weights: one full 128-dot column per lane
    const int q2 = tid >> 2;     // unit (valid < 50)
    const int r2 = tid & 3;
    const int col = (q2 < UNITS) ? q2 : 0;
    const float msk  = (q2 < UNITS && r2 < 3) ? 1.f : 0.f;
    const float tsel = (r2 == 2) ? 1.f : 0.f;
    const float* Wp = (r2 == 0) ? W_ff1 : ((r2 == 1) ? W_ff2 : W_ta);
    float w2[BBU];
    #pragma unroll
    for (int i = 0; i < BBU; ++i)
        w2[i] = msk * (Wp[i * UNITS + col] + tsel * W_tb[i * UNITS + col]);
    float bias2 = 0.f;
    if (r2 == 0)      bias2 = b_ff1[col];
    else if (r2 == 1) bias2 = b_ff2[col];
    else if (r2 == 2) bias2 = b_ta[col] + b_tb[col];
    bias2 *= msk;

    // activation constants: r2==2 -> sigmoid, else tanh
    const float kact = (r2 == 2) ? 1.4426950409f : 2.8853900818f;
    const float cact = (r2 == 2) ? 1.f : 2.f;

    if (tid < 64) h_lds[tid] = 0.f;

    float xp_cur = xproj[j1];   // t = 0
    float xp_next;
    __syncthreads();

    for (int t = 0; t < TT; ++t) {
        // prefetch next step's xproj (consumed next iteration)
        {
            const int tn = (t + 1 < TT) ? (t + 1) : t;
            xp_next = xproj[tn * BBU + j1];
        }

        // ================= phase 1: backbone =================
        float p0 = (s1 == 0) ? xp_cur : 0.f;
        float p1 = 0.f;
        #pragma unroll
        for (int q = 0; q < 25; ++q) {
            const float hv = h_lds[hbase + q];
            if (q & 1) p1 = fmaf(hv, wh[q], p1);
            else       p0 = fmaf(hv, wh[q], p0);
        }
        float a1 = p0 + p1;
        a1 += dpp_xor1(a1);
        // lecun_tanh(x) = 1.7159*tanh(0.666x); 2*0.666*log2(e) = 1.9216697945
        const float bbv = 1.7159f *
            (1.f - 2.f * __builtin_amdgcn_rcpf(
                 __builtin_amdgcn_exp2f(1.9216697945f * a1) + 1.f));
        if (s1 == 0) bb_lds[j1] = bbv;
        __syncthreads();

        // ================= phase 2: heads + h update =================
        float a0 = 0.f, b0 = 0.f, c0 = 0.f, d0 = 0.f;
        const float4* bb4 = (const float4*)bb_lds;
        #pragma unroll
        for (int rr = 0; rr < 32; ++rr) {
            const float4 v = bb4[rr];
            a0 = fmaf(v.x, w2[4 * rr + 0], a0);
            b0 = fmaf(v.y, w2[4 * rr + 1], b0);
            c0 = fmaf(v.z, w2[4 * rr + 2], c0);
            d0 = fmaf(v.w, w2[4 * rr + 3], d0);
        }
        const float a2 = ((a0 + b0) + (c0 + d0)) + bias2;
        // unified activation (tanh / sigmoid), all lanes uniform
        const float val = 1.f - cact * __builtin_amdgcn_rcpf(
                              __builtin_amdgcn_exp2f(kact * a2) + 1.f);
        const float f2v = dpp_xor1(val);   // r0 <- r1 (ff2)
        const float tiv = dpp_xor2(val);   // r0 <- r2 (t_interp)
        if (r2 == 0 && q2 < UNITS) {
            // h = f1 + ti*(f2 - f1)
            h_lds[q2 + ((q2 >= 25) ? 7 : 0)] = fmaf(tiv, f2v - val, val);
        }
        xp_cur = xp_next;
        __syncthreads();
    }

    // ---- readout: out = h @ W_out + b_out  (single wave)
    if (tid < 64) {
        float v = 0.f;
        if (tid < UNITS)
            v = h_lds[tid + ((tid >= 25) ? 7 : 0)] * W_out[tid];
        #pragma unroll
        for (int off = 1; off < 64; off <<= 1)
            v += __shfl_xor(v, off);
        if (tid == 0) out[0] = v + b_out[0];
    }
}

// ---------------------------------------------------------------------------
extern "C" void kernel_launch(void* const* d_in, const int* in_sizes, int n_in,
                              void* d_out, int out_size, void* d_ws, size_t ws_size,
                              hipStream_t stream) {
    const float* x     = (const float*)d_in[0];
    const float* W_bb  = (const float*)d_in[1];
    const float* b_bb  = (const float*)d_in[2];
    const float* W_ff1 = (const float*)d_in[3];
    const float* b_ff1 = (const float*)d_in[4];
    const float* W_ff2 = (const float*)d_in[5];
    const float* b_ff2 = (const float*)d_in[6];
    const float* W_ta  = (const float*)d_in[7];
    const float* b_ta  = (const float*)d_in[8];
    const float* W_tb  = (const float*)d_in[9];
    const float* b_tb  = (const float*)d_in[10];
    const float* W_out = (const float*)d_in[11];
    const float* b_out = (const float*)d_in[12];
    float* out = (float*)d_out;

    float* xproj = (float*)d_ws;   // TT * BBU floats = 1 MiB

    xproj_kernel<<<TT, BBU, 0, stream>>>(x, W_bb, b_bb, xproj);
    cfc_seq_kernel<<<1, 256, 0, stream>>>(W_bb,
                                          W_ff1, b_ff1, W_ff2, b_ff2,
                                          W_ta, b_ta, W_tb, b_tb,
                                          W_out, b_out, xproj, out);
}

// Round 5
// 1394.164 us; speedup vs baseline: 1.7642x; 1.4073x over previous
//
#include <hip/hip_runtime.h>
#include <math.h>

#define IN    64
#define UNITS 50
#define BBU   128
#define BATCH 256
#define TT    2048

// ---------------------------------------------------------------------------
// DPP cross-lane helpers (VALU pipe, ~4 cyc)
// quad_perm xor1 = [1,0,3,2] = 0xB1 ; xor2 = [2,3,0,1] = 0x4E
// ---------------------------------------------------------------------------
__device__ __forceinline__ float dpp_xor1(float v) {
    int r = __builtin_amdgcn_update_dpp(0, __builtin_bit_cast(int, v),
                                        0xB1, 0xF, 0xF, true);
    return __builtin_bit_cast(float, r);
}
__device__ __forceinline__ float dpp_xor2(float v) {
    int r = __builtin_amdgcn_update_dpp(0, __builtin_bit_cast(int, v),
                                        0x4E, 0xF, 0xF, true);
    return __builtin_bit_cast(float, r);
}

// ---------------------------------------------------------------------------
// Kernel A (parallel): xproj[t][j] = b_bb[j] + sum_k x[255,t,k] * W_bb[k,j]
// ---------------------------------------------------------------------------
__global__ void xproj_kernel(const float* __restrict__ x,
                             const float* __restrict__ W_bb,
                             const float* __restrict__ b_bb,
                             float* __restrict__ xproj) {
    __shared__ float xr[IN];
    const int t = blockIdx.x;
    const int j = threadIdx.x;  // 0..127
    const float* xrow = x + ((size_t)(BATCH - 1) * TT + t) * IN;
    if (j < IN) xr[j] = xrow[j];
    __syncthreads();
    float acc = b_bb[j];
    #pragma unroll
    for (int k = 0; k < IN; ++k) acc = fmaf(xr[k], W_bb[k * BBU + j], acc);
    xproj[t * BBU + j] = acc;
}

// ---------------------------------------------------------------------------
// Kernel B (sequential): 1 block, 256 threads (4 waves), 2 barriers/step.
// DS-instruction-minimized layout:
//   h_lds: half s at float offset 36*s, 25 values + 7 zero pad (b128-able)
//   bb_lds: segment g (32 floats) at offset 36*g (stagger -> distinct banks)
// Phase 1: col j1=tid>>1, half s1=tid&1: 8x ds_read_b128 + 32 FMA,
//          pair-reduce (DPP xor1), lecun_tanh, s0 writes bb.
// Phase 2: unit q2=tid>>2, segment r2=tid&3: 8x ds_read_b128 + 96 FMA
//          (3 heads share the segment reads), quad butterfly per head,
//          per-lane activation (r0:tanh f1, r1:tanh f2, r2:sigmoid t),
//          DPP gather -> r0 computes h, writes h_lds.
// ---------------------------------------------------------------------------
__launch_bounds__(256, 1)
__global__ void cfc_seq_kernel(const float* __restrict__ W_bb,
                               const float* __restrict__ W_ff1, const float* __restrict__ b_ff1,
                               const float* __restrict__ W_ff2, const float* __restrict__ b_ff2,
                               const float* __restrict__ W_ta,  const float* __restrict__ b_ta,
                               const float* __restrict__ W_tb,  const float* __restrict__ b_tb,
                               const float* __restrict__ W_out, const float* __restrict__ b_out,
                               const float* __restrict__ xproj,
                               float* __restrict__ out) {
    __shared__ __align__(16) float h_lds[72];    // halves at 0 and 36
    __shared__ __align__(16) float bb_lds[144];  // segments at 0,36,72,108

    const int tid = threadIdx.x;

    // ---- phase-1 weights: 32 recurrent weights (25 real + 7 zero)
    const int j1 = tid >> 1;
    const int s1 = tid & 1;
    float wh[32];
    #pragma unroll
    for (int q = 0; q < 32; ++q)
        wh[q] = (q < 25) ? W_bb[(IN + s1 * 25 + q) * BBU + j1] : 0.f;

    // ---- phase-2 weights: segment r2 of all three heads for unit q2
    const int q2 = tid >> 2;
    const int r2 = tid & 3;
    const int col = (q2 < UNITS) ? q2 : 0;
    const float msk = (q2 < UNITS) ? 1.f : 0.f;
    float w_f1[32], w_f2[32], w_tt[32];
    #pragma unroll
    for (int i = 0; i < 32; ++i) {
        const int row = r2 * 32 + i;
        w_f1[i] = msk * W_ff1[row * UNITS + col];
        w_f2[i] = msk * W_ff2[row * UNITS + col];
        w_tt[i] = msk * (W_ta[row * UNITS + col] + W_tb[row * UNITS + col]);
    }
    float bias2;
    if (r2 == 0)      bias2 = b_ff1[col];
    else if (r2 == 1) bias2 = b_ff2[col];
    else if (r2 == 2) bias2 = b_ta[col] + b_tb[col];
    else              bias2 = 0.f;
    bias2 *= msk;
    // activation constants: r2==2 -> sigmoid, else tanh (2x slope)
    const float kact = (r2 == 2) ? 1.4426950409f : 2.8853900818f;
    const float cact = (r2 == 2) ? 1.f : 2.f;

    if (tid < 72) h_lds[tid] = 0.f;

    float xp_cur = xproj[j1];   // t = 0
    float xp_next;
    __syncthreads();

    for (int t = 0; t < TT; ++t) {
        // prefetch next step's xproj (consumed next iteration)
        {
            const int tn = (t + 1 < TT) ? (t + 1) : t;
            xp_next = xproj[tn * BBU + j1];
        }

        // ================= phase 1: backbone =================
        {
            const float4* h4 = (const float4*)(h_lds + s1 * 36);
            float p0 = (s1 == 0) ? xp_cur : 0.f;
            float p1 = 0.f, p2 = 0.f, p3 = 0.f;
            #pragma unroll
            for (int k = 0; k < 8; ++k) {
                const float4 v = h4[k];
                p0 = fmaf(v.x, wh[4 * k + 0], p0);
                p1 = fmaf(v.y, wh[4 * k + 1], p1);
                p2 = fmaf(v.z, wh[4 * k + 2], p2);
                p3 = fmaf(v.w, wh[4 * k + 3], p3);
            }
            float a1 = (p0 + p1) + (p2 + p3);
            a1 += dpp_xor1(a1);
            // lecun_tanh: 1.7159*tanh(0.666x); 2*0.666*log2(e)=1.9216697945
            const float bbv = 1.7159f *
                (1.f - 2.f * __builtin_amdgcn_rcpf(
                     __builtin_amdgcn_exp2f(1.9216697945f * a1) + 1.f));
            if (s1 == 0) bb_lds[(j1 >> 5) * 36 + (j1 & 31)] = bbv;
        }
        __syncthreads();

        // ================= phase 2: heads + h update =================
        {
            const float4* bq = (const float4*)(bb_lds + r2 * 36);
            float f1a = 0.f, f1b = 0.f;
            float f2a = 0.f, f2b = 0.f;
            float tta = 0.f, ttb = 0.f;
            #pragma unroll
            for (int k = 0; k < 8; ++k) {
                const float4 v = bq[k];
                f1a = fmaf(v.x, w_f1[4 * k + 0], f1a);
                f2a = fmaf(v.x, w_f2[4 * k + 0], f2a);
                tta = fmaf(v.x, w_tt[4 * k + 0], tta);
                f1b = fmaf(v.y, w_f1[4 * k + 1], f1b);
                f2b = fmaf(v.y, w_f2[4 * k + 1], f2b);
                ttb = fmaf(v.y, w_tt[4 * k + 1], ttb);
                f1a = fmaf(v.z, w_f1[4 * k + 2], f1a);
                f2a = fmaf(v.z, w_f2[4 * k + 2], f2a);
                tta = fmaf(v.z, w_tt[4 * k + 2], tta);
                f1b = fmaf(v.w, w_f1[4 * k + 3], f1b);
                f2b = fmaf(v.w, w_f2[4 * k + 3], f2b);
                ttb = fmaf(v.w, w_tt[4 * k + 3], ttb);
            }
            float f1s = f1a + f1b;
            float f2s = f2a + f2b;
            float tts = tta + ttb;
            // quad butterfly: full 128-dot in every lane of the quad
            f1s += dpp_xor1(f1s);  f1s += dpp_xor2(f1s);
            f2s += dpp_xor1(f2s);  f2s += dpp_xor2(f2s);
            tts += dpp_xor1(tts);  tts += dpp_xor2(tts);
            // per-lane head selection + activation
            const float sel = (r2 == 0) ? f1s : ((r2 == 1) ? f2s : tts);
            const float a2 = sel + bias2;
            const float val = 1.f - cact * __builtin_amdgcn_rcpf(
                                  __builtin_amdgcn_exp2f(kact * a2) + 1.f);
            const float f2v = dpp_xor1(val);   // r0 <- r1 (ff2)
            const float tiv = dpp_xor2(val);   // r0 <- r2 (t_interp)
            if (r2 == 0 && q2 < UNITS) {
                // h = f1 + ti*(f2 - f1)
                h_lds[q2 + ((q2 >= 25) ? 11 : 0)] = fmaf(tiv, f2v - val, val);
            }
        }
        xp_cur = xp_next;
        __syncthreads();
    }

    // ---- readout: out = h @ W_out + b_out  (single wave)
    if (tid < 64) {
        float v = 0.f;
        if (tid < UNITS)
            v = h_lds[tid + ((tid >= 25) ? 11 : 0)] * W_out[tid];
        #pragma unroll
        for (int off = 1; off < 64; off <<= 1)
            v += __shfl_xor(v, off);
        if (tid == 0) out[0] = v + b_out[0];
    }
}

// ---------------------------------------------------------------------------
extern "C" void kernel_launch(void* const* d_in, const int* in_sizes, int n_in,
                              void* d_out, int out_size, void* d_ws, size_t ws_size,
                              hipStream_t stream) {
    const float* x     = (const float*)d_in[0];
    const float* W_bb  = (const float*)d_in[1];
    const float* b_bb  = (const float*)d_in[2];
    const float* W_ff1 = (const float*)d_in[3];
    const float* b_ff1 = (const float*)d_in[4];
    const float* W_ff2 = (const float*)d_in[5];
    const float* b_ff2 = (const float*)d_in[6];
    const float* W_ta  = (const float*)d_in[7];
    const float* b_ta  = (const float*)d_in[8];
    const float* W_tb  = (const float*)d_in[9];
    const float* b_tb  = (const float*)d_in[10];
    const float* W_out = (const float*)d_in[11];
    const float* b_out = (const float*)d_in[12];
    float* out = (float*)d_out;

    float* xproj = (float*)d_ws;   // TT * BBU floats = 1 MiB

    xproj_kernel<<<TT, BBU, 0, stream>>>(x, W_bb, b_bb, xproj);
    cfc_seq_kernel<<<1, 256, 0, stream>>>(W_bb,
                                          W_ff1, b_ff1, W_ff2, b_ff2,
                                          W_ta, b_ta, W_tb, b_tb,
                                          W_out, b_out, xproj, out);
}

// Round 6
// 1310.613 us; speedup vs baseline: 1.8766x; 1.0637x over previous
//
#include <hip/hip_runtime.h>
#include <math.h>

#define IN    64
#define UNITS 50
#define BBU   128
#define BATCH 256
#define TT    2048

// ---------------------------------------------------------------------------
// DPP cross-lane add sources (VALU pipe):
//   0xB1 quad_perm xor1, 0x4E quad_perm xor2, 0x141 row_half_mirror (8-lane)
// ---------------------------------------------------------------------------
template <int CTRL>
__device__ __forceinline__ float dpp_mv(float v) {
    int r = __builtin_amdgcn_update_dpp(0, __builtin_bit_cast(int, v),
                                        CTRL, 0xF, 0xF, true);
    return __builtin_bit_cast(float, r);
}

__device__ __forceinline__ float tanh_fast(float x) {
    // tanh(x) = 1 - 2/(exp2(2*log2e*x)+1)
    return 1.f - 2.f * __builtin_amdgcn_rcpf(
                    __builtin_amdgcn_exp2f(2.8853900818f * x) + 1.f);
}
__device__ __forceinline__ float sigm_fast(float x) {
    // sigmoid(x) = 1 - 1/(exp2(log2e*x)+1)
    return 1.f - __builtin_amdgcn_rcpf(
                    __builtin_amdgcn_exp2f(1.4426950409f * x) + 1.f);
}

// ---------------------------------------------------------------------------
// Kernel A (parallel): xproj[t][j] = b_bb[j] + sum_k x[255,t,k] * W_bb[k,j]
// ---------------------------------------------------------------------------
__global__ void xproj_kernel(const float* __restrict__ x,
                             const float* __restrict__ W_bb,
                             const float* __restrict__ b_bb,
                             float* __restrict__ xproj) {
    __shared__ float xr[IN];
    const int t = blockIdx.x;
    const int j = threadIdx.x;  // 0..127
    const float* xrow = x + ((size_t)(BATCH - 1) * TT + t) * IN;
    if (j < IN) xr[j] = xrow[j];
    __syncthreads();
    float acc = b_bb[j];
    #pragma unroll
    for (int k = 0; k < IN; ++k) acc = fmaf(xr[k], W_bb[k * BBU + j], acc);
    xproj[t * BBU + j] = acc;
}

// ---------------------------------------------------------------------------
// Kernel B (sequential): 1 block, 512 threads (8 waves, 2/SIMD), 2 barriers.
// Register-budget design: 64 weight VGPRs/lane (16 phase-1 + 48 phase-2).
//
// LDS (segment-staggered by 20 floats = conflict-free bank quads):
//   h_lds : 4 segs @20f, seg s holds units s*13..s*13+12 (+3 zero pads)
//   bb_lds: 8 segs @20f, seg g holds bb[16g..16g+15] (+4 pads, never read)
//
// Phase 1: col j1=tid>>2 (0..127), quarter s1=tid&3 owns 13 h-values:
//   4x ds_read_b128 + 16 FMA, quad reduce (xor1,xor2), lecun_tanh,
//   s1==0 writes bb seg.
// Phase 2: oct o2=tid>>3 (unit, <50), lane g2=tid&7 owns bb seg of 16 for
//   ALL 3 heads: 4x ds_read_b128 + 48 FMA (6 chains), 8-lane reduce per head
//   (xor1,xor2,half_mirror) -> all lanes hold f1,f2,tt dots; uniform
//   activations; g2==0 writes h[unit].
// ---------------------------------------------------------------------------
__launch_bounds__(512, 2)
__global__ void cfc_seq_kernel(const float* __restrict__ W_bb,
                               const float* __restrict__ W_ff1, const float* __restrict__ b_ff1,
                               const float* __restrict__ W_ff2, const float* __restrict__ b_ff2,
                               const float* __restrict__ W_ta,  const float* __restrict__ b_ta,
                               const float* __restrict__ W_tb,  const float* __restrict__ b_tb,
                               const float* __restrict__ W_out, const float* __restrict__ b_out,
                               const float* __restrict__ xproj,
                               float* __restrict__ out) {
    __shared__ __align__(16) float h_lds[80];    // 4 segs at 20*s
    __shared__ __align__(16) float bb_lds[160];  // 8 segs at 20*g

    const int tid = threadIdx.x;

    // ---- phase-1 weights: 13 real (+3 zero) recurrent weights
    const int j1 = tid >> 2;          // 0..127
    const int s1 = tid & 3;
    float wh[16];
    #pragma unroll
    for (int q = 0; q < 16; ++q) {
        const int u = s1 * 13 + q;
        wh[q] = (q < 13 && u < UNITS) ? W_bb[(IN + u) * BBU + j1] : 0.f;
    }
    const int bbslot = 20 * (j1 >> 4) + (j1 & 15);

    // ---- phase-2 weights: seg g2 (16 floats) of all three heads, unit o2
    const int o2 = tid >> 3;          // 0..63 (unit, valid < 50)
    const int g2 = tid & 7;
    const int col = (o2 < UNITS) ? o2 : 0;
    const float msk = (o2 < UNITS) ? 1.f : 0.f;
    float w_f1[16], w_f2[16], w_tt[16];
    #pragma unroll
    for (int i = 0; i < 16; ++i) {
        const int row = g2 * 16 + i;
        w_f1[i] = msk * W_ff1[row * UNITS + col];
        w_f2[i] = msk * W_ff2[row * UNITS + col];
        w_tt[i] = msk * (W_ta[row * UNITS + col] + W_tb[row * UNITS + col]);
    }
    const float bi_f1 = b_ff1[col];
    const float bi_f2 = b_ff2[col];
    const float bi_tt = b_ta[col] + b_tb[col];
    const int hslot = 20 * (col / 13) + (col % 13);

    if (tid < 80) h_lds[tid] = 0.f;   // h + pads

    float xp_cur = xproj[j1];         // t = 0
    float xp_next;
    __syncthreads();

    for (int t = 0; t < TT; ++t) {
        // prefetch next step's xproj (consumed next iteration)
        {
            const int tn = (t + 1 < TT) ? (t + 1) : t;
            xp_next = xproj[tn * BBU + j1];
        }

        // ================= phase 1: backbone =================
        {
            const float4* h4 = (const float4*)(h_lds + s1 * 20);
            float p0 = (s1 == 0) ? xp_cur : 0.f;
            float p1 = 0.f, p2 = 0.f, p3 = 0.f;
            #pragma unroll
            for (int k = 0; k < 4; ++k) {
                const float4 v = h4[k];
                p0 = fmaf(v.x, wh[4 * k + 0], p0);
                p1 = fmaf(v.y, wh[4 * k + 1], p1);
                p2 = fmaf(v.z, wh[4 * k + 2], p2);
                p3 = fmaf(v.w, wh[4 * k + 3], p3);
            }
            float a1 = (p0 + p1) + (p2 + p3);
            a1 += dpp_mv<0xB1>(a1);
            a1 += dpp_mv<0x4E>(a1);
            // lecun_tanh: 1.7159*tanh(0.666x); 2*0.666*log2(e)=1.9216697945
            const float bbv = 1.7159f *
                (1.f - 2.f * __builtin_amdgcn_rcpf(
                     __builtin_amdgcn_exp2f(1.9216697945f * a1) + 1.f));
            if (s1 == 0) bb_lds[bbslot] = bbv;
        }
        __syncthreads();

        // ================= phase 2: heads + h update =================
        {
            const float4* b4 = (const float4*)(bb_lds + g2 * 20);
            float f1a = 0.f, f2a = 0.f, tta = 0.f;
            float f1b = 0.f, f2b = 0.f, ttb = 0.f;
            #pragma unroll
            for (int k = 0; k < 4; ++k) {
                const float4 v = b4[k];
                f1a = fmaf(v.x, w_f1[4 * k + 0], f1a);
                f2a = fmaf(v.x, w_f2[4 * k + 0], f2a);
                tta = fmaf(v.x, w_tt[4 * k + 0], tta);
                f1b = fmaf(v.y, w_f1[4 * k + 1], f1b);
                f2b = fmaf(v.y, w_f2[4 * k + 1], f2b);
                ttb = fmaf(v.y, w_tt[4 * k + 1], ttb);
                f1a = fmaf(v.z, w_f1[4 * k + 2], f1a);
                f2a = fmaf(v.z, w_f2[4 * k + 2], f2a);
                tta = fmaf(v.z, w_tt[4 * k + 2], tta);
                f1b = fmaf(v.w, w_f1[4 * k + 3], f1b);
                f2b = fmaf(v.w, w_f2[4 * k + 3], f2b);
                ttb = fmaf(v.w, w_tt[4 * k + 3], ttb);
            }
            float sf1 = f1a + f1b;
            float sf2 = f2a + f2b;
            float stt = tta + ttb;
            // 8-lane reduce (full dot in every lane of the oct)
            sf1 += dpp_mv<0xB1>(sf1); sf1 += dpp_mv<0x4E>(sf1); sf1 += dpp_mv<0x141>(sf1);
            sf2 += dpp_mv<0xB1>(sf2); sf2 += dpp_mv<0x4E>(sf2); sf2 += dpp_mv<0x141>(sf2);
            stt += dpp_mv<0xB1>(stt); stt += dpp_mv<0x4E>(stt); stt += dpp_mv<0x141>(stt);
            // uniform activations (all lanes; only g2==0's result is stored)
            const float v1 = tanh_fast(sf1 + bi_f1);
            const float v2 = tanh_fast(sf2 + bi_f2);
            const float ti = sigm_fast(stt + bi_tt);
            if (g2 == 0 && o2 < UNITS) {
                // h = f1 + ti*(f2 - f1)
                h_lds[hslot] = fmaf(ti, v2 - v1, v1);
            }
        }
        xp_cur = xp_next;
        __syncthreads();
    }

    // ---- readout: out = h @ W_out + b_out  (single wave)
    if (tid < 64) {
        float v = 0.f;
        if (tid < UNITS)
            v = h_lds[20 * (tid / 13) + (tid % 13)] * W_out[tid];
        #pragma unroll
        for (int off = 1; off < 64; off <<= 1)
            v += __shfl_xor(v, off);
        if (tid == 0) out[0] = v + b_out[0];
    }
}

// ---------------------------------------------------------------------------
extern "C" void kernel_launch(void* const* d_in, const int* in_sizes, int n_in,
                              void* d_out, int out_size, void* d_ws, size_t ws_size,
                              hipStream_t stream) {
    const float* x     = (const float*)d_in[0];
    const float* W_bb  = (const float*)d_in[1];
    const float* b_bb  = (const float*)d_in[2];
    const float* W_ff1 = (const float*)d_in[3];
    const float* b_ff1 = (const float*)d_in[4];
    const float* W_ff2 = (const float*)d_in[5];
    const float* b_ff2 = (const float*)d_in[6];
    const float* W_ta  = (const float*)d_in[7];
    const float* b_ta  = (const float*)d_in[8];
    const float* W_tb  = (const float*)d_in[9];
    const float* b_tb  = (const float*)d_in[10];
    const float* W_out = (const float*)d_in[11];
    const float* b_out = (const float*)d_in[12];
    float* out = (float*)d_out;

    float* xproj = (float*)d_ws;   // TT * BBU floats = 1 MiB

    xproj_kernel<<<TT, BBU, 0, stream>>>(x, W_bb, b_bb, xproj);
    cfc_seq_kernel<<<1, 512, 0, stream>>>(W_bb,
                                          W_ff1, b_ff1, W_ff2, b_ff2,
                                          W_ta, b_ta, W_tb, b_tb,
                                          W_out, b_out, xproj, out);
}

// Round 8
// 1205.181 us; speedup vs baseline: 2.0408x; 1.0875x over previous
//
#include <hip/hip_runtime.h>
#include <math.h>

#define IN    64
#define UNITS 50
#define BBU   128
#define BATCH 256
#define TT    2048

typedef float f32x2 __attribute__((ext_vector_type(2)));

// ---------------------------------------------------------------------------
// DPP cross-lane add sources (VALU pipe):
//   0xB1 quad_perm xor1, 0x4E quad_perm xor2, 0x141 row_half_mirror (8-lane)
// ---------------------------------------------------------------------------
template <int CTRL>
__device__ __forceinline__ float dpp_mv(float v) {
    int r = __builtin_amdgcn_update_dpp(0, __builtin_bit_cast(int, v),
                                        CTRL, 0xF, 0xF, true);
    return __builtin_bit_cast(float, r);
}

// Opaque register pin: the asm result cannot be rematerialized by the
// allocator, so the value MUST stay live in a VGPR across the t-loop.
__device__ __forceinline__ void pin2(f32x2 &v) {
    float a = v.x, b = v.y;
    asm volatile("" : "+v"(a), "+v"(b));
    v.x = a; v.y = b;
}

__device__ __forceinline__ f32x2 fma2(f32x2 a, f32x2 b, f32x2 c) {
    return __builtin_elementwise_fma(a, b, c);   // v_pk_fma_f32
}

// ---------------------------------------------------------------------------
// Kernel A (parallel): xproj[t][j] = b_bb[j] + sum_k x[255,t,k] * W_bb[k,j]
// ---------------------------------------------------------------------------
__global__ void xproj_kernel(const float* __restrict__ x,
                             const float* __restrict__ W_bb,
                             const float* __restrict__ b_bb,
                             float* __restrict__ xproj) {
    __shared__ float xr[IN];
    const int t = blockIdx.x;
    const int j = threadIdx.x;  // 0..127
    const float* xrow = x + ((size_t)(BATCH - 1) * TT + t) * IN;
    if (j < IN) xr[j] = xrow[j];
    __syncthreads();
    float acc = b_bb[j];
    #pragma unroll
    for (int k = 0; k < IN; ++k) acc = fmaf(xr[k], W_bb[k * BBU + j], acc);
    xproj[t * BBU + j] = acc;
}

// ---------------------------------------------------------------------------
// Kernel B (sequential): 1 block, 512 threads (8 waves, 2/SIMD), 2 barriers.
// Weights pinned in VGPRs (asm-opaque), packed v_pk_fma_f32 math.
//
// LDS (segment-staggered by 20 floats = conflict-free bank quads):
//   h_lds : 4 segs @20f, seg s holds units s*13..s*13+12 (+pads, zero)
//   bb_lds: 8 segs @20f, seg g holds bb[16g..16g+15]
//
// Phase 1: col j1=tid>>2 (0..127), quarter s1=tid&3 owns 13 h-values:
//   4x ds_read_b128 + 8 pk_fma, quad reduce (xor1,xor2), lecun_tanh,
//   s1==0 writes bb seg.
// Phase 2 (only octs with o2<50): lane g2=tid&7 owns bb seg of 16 for ALL
//   3 heads: 4x ds_read_b128 + 24 pk_fma, 8-lane reduce per head
//   (xor1,xor2,half_mirror), per-lane head select + ONE activation
//   (g0:tanh f1, g1:tanh f2, g2:sigmoid t), 2 DPP gathers -> g0 writes h.
// ---------------------------------------------------------------------------
__launch_bounds__(512, 2)
__global__ void cfc_seq_kernel(const float* __restrict__ W_bb,
                               const float* __restrict__ W_ff1, const float* __restrict__ b_ff1,
                               const float* __restrict__ W_ff2, const float* __restrict__ b_ff2,
                               const float* __restrict__ W_ta,  const float* __restrict__ b_ta,
                               const float* __restrict__ W_tb,  const float* __restrict__ b_tb,
                               const float* __restrict__ W_out, const float* __restrict__ b_out,
                               const float* __restrict__ xproj,
                               float* __restrict__ out) {
    __shared__ __align__(16) float h_lds[80];    // 4 segs at 20*s
    __shared__ __align__(16) float bb_lds[160];  // 8 segs at 20*g

    const int tid = threadIdx.x;

    // ---- phase-1 weights: 13 real (+3 zero) recurrent weights, as f32x2[8]
    const int j1 = tid >> 2;          // 0..127
    const int s1 = tid & 3;
    f32x2 wh2[8];
    #pragma unroll
    for (int q = 0; q < 16; ++q) {
        const int u = s1 * 13 + q;
        const float w = (q < 13 && u < UNITS) ? W_bb[(IN + u) * BBU + j1] : 0.f;
        if (q & 1) wh2[q >> 1].y = w; else wh2[q >> 1].x = w;
    }
    const int bbslot = 20 * (j1 >> 4) + (j1 & 15);

    // ---- phase-2 weights: seg g2 (16 floats) of all three heads, unit o2
    const int o2 = tid >> 3;          // 0..63 (unit, valid < 50)
    const int g2 = tid & 7;
    const int col = (o2 < UNITS) ? o2 : 0;
    f32x2 wf1[8], wf2[8], wtt[8];
    #pragma unroll
    for (int i = 0; i < 16; ++i) {
        const int row = g2 * 16 + i;
        const float a = W_ff1[row * UNITS + col];
        const float b = W_ff2[row * UNITS + col];
        const float c = W_ta[row * UNITS + col] + W_tb[row * UNITS + col];
        if (i & 1) { wf1[i >> 1].y = a; wf2[i >> 1].y = b; wtt[i >> 1].y = c; }
        else       { wf1[i >> 1].x = a; wf2[i >> 1].x = b; wtt[i >> 1].x = c; }
    }
    // per-lane bias + activation constants (g2==2 -> sigmoid, else tanh)
    float bias2;
    if (g2 == 0)      bias2 = b_ff1[col];
    else if (g2 == 1) bias2 = b_ff2[col];
    else              bias2 = b_ta[col] + b_tb[col];
    const float kact = (g2 == 2) ? 1.4426950409f : 2.8853900818f;
    const float cact = (g2 == 2) ? 1.f : 2.f;
    const int hslot = 20 * (col / 13) + (col % 13);

    // ---- pin every weight into a VGPR (defeats remat/sinking)
    #pragma unroll
    for (int i = 0; i < 8; ++i) {
        pin2(wh2[i]); pin2(wf1[i]); pin2(wf2[i]); pin2(wtt[i]);
    }

    if (tid < 80) h_lds[tid] = 0.f;   // h + pads

    float xp_cur = xproj[j1];         // t = 0
    float xp_next;
    __syncthreads();

    for (int t = 0; t < TT; ++t) {
        // prefetch next step's xproj (consumed next iteration)
        {
            const int tn = (t + 1 < TT) ? (t + 1) : t;
            xp_next = xproj[tn * BBU + j1];
        }

        // ================= phase 1: backbone =================
        {
            const float4* h4 = (const float4*)(h_lds + s1 * 20);
            f32x2 acc = {(s1 == 0) ? xp_cur : 0.f, 0.f};
            #pragma unroll
            for (int k = 0; k < 4; ++k) {
                const float4 v = h4[k];
                const f32x2 lo = {v.x, v.y};
                const f32x2 hi = {v.z, v.w};
                acc = fma2(lo, wh2[2 * k + 0], acc);
                acc = fma2(hi, wh2[2 * k + 1], acc);
            }
            float a1 = acc.x + acc.y;
            a1 += dpp_mv<0xB1>(a1);
            a1 += dpp_mv<0x4E>(a1);
            // lecun_tanh: 1.7159*tanh(0.666x); 2*0.666*log2(e)=1.9216697945
            const float bbv = 1.7159f *
                (1.f - 2.f * __builtin_amdgcn_rcpf(
                     __builtin_amdgcn_exp2f(1.9216697945f * a1) + 1.f));
            if (s1 == 0) bb_lds[bbslot] = bbv;
        }
        __syncthreads();

        // ================= phase 2: heads + h update =================
        if (o2 < UNITS) {
            const float4* b4 = (const float4*)(bb_lds + g2 * 20);
            f32x2 af1 = {0.f, 0.f}, af2 = {0.f, 0.f}, att = {0.f, 0.f};
            #pragma unroll
            for (int k = 0; k < 4; ++k) {
                const float4 v = b4[k];
                const f32x2 lo = {v.x, v.y};
                const f32x2 hi = {v.z, v.w};
                af1 = fma2(lo, wf1[2 * k + 0], af1);
                af2 = fma2(lo, wf2[2 * k + 0], af2);
                att = fma2(lo, wtt[2 * k + 0], att);
                af1 = fma2(hi, wf1[2 * k + 1], af1);
                af2 = fma2(hi, wf2[2 * k + 1], af2);
                att = fma2(hi, wtt[2 * k + 1], att);
            }
            float sf1 = af1.x + af1.y;
            float sf2 = af2.x + af2.y;
            float stt = att.x + att.y;
            // 8-lane butterfly reduce per head
            sf1 += dpp_mv<0xB1>(sf1); sf1 += dpp_mv<0x4E>(sf1); sf1 += dpp_mv<0x141>(sf1);
            sf2 += dpp_mv<0xB1>(sf2); sf2 += dpp_mv<0x4E>(sf2); sf2 += dpp_mv<0x141>(sf2);
            stt += dpp_mv<0xB1>(stt); stt += dpp_mv<0x4E>(stt); stt += dpp_mv<0x141>(stt);
            // per-lane head select + ONE activation
            const float sel = (g2 == 0) ? sf1 : ((g2 == 1) ? sf2 : stt);
            const float a2 = sel + bias2;
            const float val = 1.f - cact * __builtin_amdgcn_rcpf(
                                  __builtin_amdgcn_exp2f(kact * a2) + 1.f);
            const float f2v = dpp_mv<0xB1>(val);   // g0 <- g1 (ff2)
            const float tiv = dpp_mv<0x4E>(val);   // g0 <- g2 (t_interp)
            if (g2 == 0) {
                // h = f1 + ti*(f2 - f1)
                h_lds[hslot] = fmaf(tiv, f2v - val, val);
            }
        }
        xp_cur = xp_next;
        __syncthreads();
    }

    // ---- readout: out = h @ W_out + b_out  (single wave)
    if (tid < 64) {
        float v = 0.f;
        if (tid < UNITS)
            v = h_lds[20 * (tid / 13) + (tid % 13)] * W_out[tid];
        #pragma unroll
        for (int off = 1; off < 64; off <<= 1)
            v += __shfl_xor(v, off);
        if (tid == 0) out[0] = v + b_out[0];
    }
}

// ---------------------------------------------------------------------------
extern "C" void kernel_launch(void* const* d_in, const int* in_sizes, int n_in,
                              void* d_out, int out_size, void* d_ws, size_t ws_size,
                              hipStream_t stream) {
    const float* x     = (const float*)d_in[0];
    const float* W_bb  = (const float*)d_in[1];
    const float* b_bb  = (const float*)d_in[2];
    const float* W_ff1 = (const float*)d_in[3];
    const float* b_ff1 = (const float*)d_in[4];
    const float* W_ff2 = (const float*)d_in[5];
    const float* b_ff2 = (const float*)d_in[6];
    const float* W_ta  = (const float*)d_in[7];
    const float* b_ta  = (const float*)d_in[8];
    const float* W_tb  = (const float*)d_in[9];
    const float* b_tb  = (const float*)d_in[10];
    const float* W_out = (const float*)d_in[11];
    const float* b_out = (const float*)d_in[12];
    float* out = (float*)d_out;

    float* xproj = (float*)d_ws;   // TT * BBU floats = 1 MiB

    xproj_kernel<<<TT, BBU, 0, stream>>>(x, W_bb, b_bb, xproj);
    cfc_seq_kernel<<<1, 512, 0, stream>>>(W_bb,
                                          W_ff1, b_ff1, W_ff2, b_ff2,
                                          W_ta, b_ta, W_tb, b_tb,
                                          W_out, b_out, xproj, out);
}